// Round 4
// baseline (30.959 us; speedup 1.0000x reference)
//
#include <hip/hip_runtime.h>

#define EPS    1e-5f
#define NSLOPE 0.01f
#define B 4
#define N 256
#define F 128

// workspace float layout
#define WS_WE0 0                 // we0[g]*s1[g]            (128)
#define WS_WE1 128               // we1[g]*s1[g]            (128)
#define WS_PF0 256               // weff[0][g]              (128)
#define WS_PF1 384               // weff[1][g]              (128)
#define WS_C   512               // c[0..1]
#define WS_HL  1024              // hl''[row,g] = hl*s1+t1  (B*N*F)
#define WS_HR  (WS_HL + B*N*F)   // hr'[row,g]  = hr*s1     (B*N*F)

// ---------------------------------------------------------------- prep_all
// grid 257 blocks x 128 threads.
// blocks 0..255: hl/hr. 16 row-chunks (64 rows) x 16 g-chunks (8 g).
//   Node tile (64 rows x 128 f = 32 KB) staged in LDS via coalesced float4
//   loads + XOR swizzle (slot ^= row&7) so per-lane row reads are
//   minimum-aliasing b128 (no 32-way stride-512B bank conflict).
//   Weight reads wave-uniform -> s_load (scalar pipe, free).
// block 256: fold affine head/tail into WE/PF/C.
__global__ __launch_bounds__(128) void prep_all(
    const float* __restrict__ node, const float* __restrict__ w1,
    const float* __restrict__ g1, const float* __restrict__ b1,
    const float* __restrict__ m1, const float* __restrict__ v1,
    const float* __restrict__ w2, const float* __restrict__ g2,
    const float* __restrict__ b2, const float* __restrict__ m2,
    const float* __restrict__ v2, const float* __restrict__ pw,
    const float* __restrict__ pb, float* __restrict__ ws) {
  if (blockIdx.x == 256) {
    __shared__ float s2s[F], t2s[F];
    int g = threadIdx.x;
    float s1v = g1[g] / sqrtf(v1[g] + EPS);
    ws[WS_WE0 + g] = w1[g * 258 + 0] * s1v;
    ws[WS_WE1 + g] = w1[g * 258 + 1] * s1v;
    float s2v = g2[g] / sqrtf(v2[g] + EPS);
    s2s[g] = s2v;
    t2s[g] = b2[g] - m2[g] * s2v;
    __syncthreads();
    float a0 = 0.f, a1 = 0.f;
    for (int f = 0; f < F; ++f) {
      float wv = w2[f * F + g];               // coalesced (g fastest)
      a0 = fmaf(pw[f]     * s2s[f], wv, a0);
      a1 = fmaf(pw[F + f] * s2s[f], wv, a1);
    }
    ws[WS_PF0 + g] = a0;
    ws[WS_PF1 + g] = a1;
    if (g < 2) {
      float c = pb[g];
      for (int f = 0; f < F; ++f) c += pw[g * F + f] * t2s[f];
      ws[WS_C + g] = c;
    }
    return;
  }
  __shared__ float4 ns4[64 * 32];              // 32 KB, xor-swizzled
  int t = threadIdx.x;
  int rc = blockIdx.x >> 4;                    // 16 row chunks of 64
  int gc = blockIdx.x & 15;                    // 16 g chunks of 8
  int r0 = rc * 64;
  const float4* node4 = reinterpret_cast<const float4*>(node) + (size_t)r0 * 32;
  #pragma unroll
  for (int k = 0; k < 16; ++k) {
    int L = k * 128 + t;                       // coalesced global float4 id
    int row = L >> 5, s = L & 31;
    ns4[row * 32 + (s ^ (row & 7))] = node4[L];
  }
  __syncthreads();
  int lane = t & 63;
  int wv = __builtin_amdgcn_readfirstlane(t >> 6);  // 0..1, SGPR
  int g0 = gc * 8 + wv * 4;
  int lbase = lane * 32;
  int lx = lane & 7;
  float accl[4] = {0.f, 0.f, 0.f, 0.f};
  float accr[4] = {0.f, 0.f, 0.f, 0.f};
  #pragma unroll 8
  for (int q = 0; q < 32; ++q) {
    float4 nv = ns4[lbase + (q ^ lx)];         // min-aliasing b128
    #pragma unroll
    for (int k = 0; k < 4; ++k) {
      const float* wrow = w1 + (size_t)(g0 + k) * 258;   // wave-uniform -> s_load
      float2 wl0 = *reinterpret_cast<const float2*>(wrow + 2 + 4 * q);
      float2 wl1 = *reinterpret_cast<const float2*>(wrow + 4 + 4 * q);
      float2 wr0 = *reinterpret_cast<const float2*>(wrow + 130 + 4 * q);
      float2 wr1 = *reinterpret_cast<const float2*>(wrow + 132 + 4 * q);
      accl[k] = fmaf(nv.x, wl0.x, accl[k]);
      accl[k] = fmaf(nv.y, wl0.y, accl[k]);
      accl[k] = fmaf(nv.z, wl1.x, accl[k]);
      accl[k] = fmaf(nv.w, wl1.y, accl[k]);
      accr[k] = fmaf(nv.x, wr0.x, accr[k]);
      accr[k] = fmaf(nv.y, wr0.y, accr[k]);
      accr[k] = fmaf(nv.z, wr1.x, accr[k]);
      accr[k] = fmaf(nv.w, wr1.y, accr[k]);
    }
  }
  int row = r0 + lane;
  float4 ol, orr;
  #pragma unroll
  for (int k = 0; k < 4; ++k) {
    int g = g0 + k;
    float s1v = g1[g] / sqrtf(v1[g] + EPS);    // wave-uniform, tiny
    float t1v = b1[g] - m1[g] * s1v;
    (&ol.x)[k]  = fmaf(accl[k], s1v, t1v);
    (&orr.x)[k] = accr[k] * s1v;
  }
  *reinterpret_cast<float4*>(ws + WS_HL + (size_t)row * F + g0) = ol;
  *reinterpret_cast<float4*>(ws + WS_HR + (size_t)row * F + g0) = orr;
}

// ---------------------------------------------------------------- main
// grid (8,8,B), block 256: 32x32 (i,j) tile, 2x2 outputs per thread.
// hl/hr tiles staged in LDS; WE/PF/C read as wave-uniform globals (s_load).
__global__ __launch_bounds__(256) void fused_main(
    const float* __restrict__ edge,
    const float* __restrict__ ws, float* __restrict__ out) {
  __shared__ float hls[32][132];
  __shared__ float hrs[32][132];
  int b = blockIdx.z, i0 = blockIdx.y * 32, j0 = blockIdx.x * 32;
  int t = threadIdx.x;
  int ti = t >> 4, tj = t & 15;
  int i1 = i0 + ti, i2 = i1 + 16, j1 = j0 + tj, j2 = j1 + 16;
  // issue edge loads early (independent of LDS staging)
  float2 e00 = *reinterpret_cast<const float2*>(edge + ((size_t)(b * N + i1) * N + j1) * 2);
  float2 e01 = *reinterpret_cast<const float2*>(edge + ((size_t)(b * N + i1) * N + j2) * 2);
  float2 e10 = *reinterpret_cast<const float2*>(edge + ((size_t)(b * N + i2) * N + j1) * 2);
  float2 e11 = *reinterpret_cast<const float2*>(edge + ((size_t)(b * N + i2) * N + j2) * 2);
  {
    const float* hl = ws + WS_HL;
    const float* hr = ws + WS_HR;
    int r = t >> 3, cq = (t & 7) * 16;
    const float* sl = hl + (size_t)(b * N + i0 + r) * F + cq;
    const float* sr = hr + (size_t)(b * N + j0 + r) * F + cq;
    #pragma unroll
    for (int k = 0; k < 4; ++k) {
      *reinterpret_cast<float4*>(&hls[r][cq + 4 * k]) =
          *reinterpret_cast<const float4*>(sl + 4 * k);
      *reinterpret_cast<float4*>(&hrs[r][cq + 4 * k]) =
          *reinterpret_cast<const float4*>(sr + 4 * k);
    }
  }
  __syncthreads();
  const float4* W0p = reinterpret_cast<const float4*>(ws + WS_WE0);  // uniform -> s_load
  const float4* W1p = reinterpret_cast<const float4*>(ws + WS_WE1);
  const float4* P0p = reinterpret_cast<const float4*>(ws + WS_PF0);
  const float4* P1p = reinterpret_cast<const float4*>(ws + WS_PF1);
  float a00x = 0.f, a00y = 0.f, a01x = 0.f, a01y = 0.f;
  float a10x = 0.f, a10y = 0.f, a11x = 0.f, a11y = 0.f;
  #pragma unroll 4
  for (int gq = 0; gq < F / 4; ++gq) {
    int g = gq * 4;
    float4 L0 = *reinterpret_cast<const float4*>(&hls[ti][g]);
    float4 L1 = *reinterpret_cast<const float4*>(&hls[ti + 16][g]);
    float4 R0 = *reinterpret_cast<const float4*>(&hrs[tj][g]);
    float4 R1 = *reinterpret_cast<const float4*>(&hrs[tj + 16][g]);
    float4 W0 = W0p[gq];
    float4 W1 = W1p[gq];
    float4 P0 = P0p[gq];
    float4 P1 = P1p[gq];
#define DO_COMP(K)                                                             \
    {                                                                          \
      float w0 = W0.K, w1v = W1.K, p0 = P0.K, p1 = P1.K;                       \
      float v;                                                                 \
      v = L0.K + R0.K; v = fmaf(e00.x, w0, v); v = fmaf(e00.y, w1v, v);        \
      v = fmaxf(v, NSLOPE * v);                                                \
      a00x = fmaf(p0, v, a00x); a00y = fmaf(p1, v, a00y);                      \
      v = L0.K + R1.K; v = fmaf(e01.x, w0, v); v = fmaf(e01.y, w1v, v);        \
      v = fmaxf(v, NSLOPE * v);                                                \
      a01x = fmaf(p0, v, a01x); a01y = fmaf(p1, v, a01y);                      \
      v = L1.K + R0.K; v = fmaf(e10.x, w0, v); v = fmaf(e10.y, w1v, v);        \
      v = fmaxf(v, NSLOPE * v);                                                \
      a10x = fmaf(p0, v, a10x); a10y = fmaf(p1, v, a10y);                      \
      v = L1.K + R1.K; v = fmaf(e11.x, w0, v); v = fmaf(e11.y, w1v, v);        \
      v = fmaxf(v, NSLOPE * v);                                                \
      a11x = fmaf(p0, v, a11x); a11y = fmaf(p1, v, a11y);                      \
    }
    DO_COMP(x) DO_COMP(y) DO_COMP(z) DO_COMP(w)
#undef DO_COMP
  }
  float c0 = ws[WS_C + 0], c1 = ws[WS_C + 1];
  float2 o;
  o.x = a00x + c0; o.y = a00y + c1;
  *reinterpret_cast<float2*>(out + ((size_t)(b * N + i1) * N + j1) * 2) = o;
  o.x = a01x + c0; o.y = a01y + c1;
  *reinterpret_cast<float2*>(out + ((size_t)(b * N + i1) * N + j2) * 2) = o;
  o.x = a10x + c0; o.y = a10y + c1;
  *reinterpret_cast<float2*>(out + ((size_t)(b * N + i2) * N + j1) * 2) = o;
  o.x = a11x + c0; o.y = a11y + c1;
  *reinterpret_cast<float2*>(out + ((size_t)(b * N + i2) * N + j2) * 2) = o;
}

extern "C" void kernel_launch(void* const* d_in, const int* in_sizes, int n_in,
                              void* d_out, int out_size, void* d_ws, size_t ws_size,
                              hipStream_t stream) {
  const float* node = (const float*)d_in[0];
  const float* edge = (const float*)d_in[1];
  const float* w1   = (const float*)d_in[2];
  const float* g1   = (const float*)d_in[3];
  const float* b1   = (const float*)d_in[4];
  const float* m1   = (const float*)d_in[5];
  const float* v1   = (const float*)d_in[6];
  const float* w2   = (const float*)d_in[7];
  const float* g2   = (const float*)d_in[8];
  const float* b2   = (const float*)d_in[9];
  const float* m2   = (const float*)d_in[10];
  const float* v2   = (const float*)d_in[11];
  const float* pw   = (const float*)d_in[12];
  const float* pb   = (const float*)d_in[13];
  float* ws  = (float*)d_ws;
  float* out = (float*)d_out;

  prep_all<<<257, 128, 0, stream>>>(node, w1, g1, b1, m1, v1, w2, g2, b2, m2,
                                    v2, pw, pb, ws);
  fused_main<<<dim3(N / 32, N / 32, B), 256, 0, stream>>>(edge, ws, out);
}

// Round 5
// 25.506 us; speedup vs baseline: 1.2138x; 1.2138x over previous
//
#include <hip/hip_runtime.h>

#define EPS    1e-5f
#define NSLOPE 0.01f
#define B 4
#define N 256
#define F 128

// workspace float layout
#define WS_WE0 0                 // we0[g]*s1[g]            (128)
#define WS_WE1 128               // we1[g]*s1[g]            (128)
#define WS_PF0 256               // weff[0][g]              (128)
#define WS_PF1 384               // weff[1][g]              (128)
#define WS_C   512               // c[0..1]
#define WS_HL  1024              // hl''[row,g] = hl*s1+t1  (B*N*F)
#define WS_HR  (WS_HL + B*N*F)   // hr'[row,g]  = hr*s1     (B*N*F)

// ---------------------------------------------------------------- prep_all
// grid 257 blocks x 128 threads.
// blocks 0..255: hl/hr. 16 row-chunks (64 rows) x 16 g-chunks (8 g).
//   Node tile 64x128 staged in LDS, XOR-swizzled (read at slot q^lx holds
//   column q -> per-lane b128 reads are conflict-free).
//   Weight rows for the block's 8 g staged in LDS (coalesced loads), read
//   back at wave-uniform addresses -> ds broadcast, conflict-free, no s_load
//   storm on the scalar pipe.
// block 256: fold affine head/tail into WE/PF/C.
__global__ __launch_bounds__(128) void prep_all(
    const float* __restrict__ node, const float* __restrict__ w1,
    const float* __restrict__ g1, const float* __restrict__ b1,
    const float* __restrict__ m1, const float* __restrict__ v1,
    const float* __restrict__ w2, const float* __restrict__ g2,
    const float* __restrict__ b2, const float* __restrict__ m2,
    const float* __restrict__ v2, const float* __restrict__ pw,
    const float* __restrict__ pb, float* __restrict__ ws) {
  if (blockIdx.x == 256) {
    __shared__ float s2s[F], t2s[F];
    int g = threadIdx.x;
    float s1v = g1[g] / sqrtf(v1[g] + EPS);
    ws[WS_WE0 + g] = w1[g * 258 + 0] * s1v;
    ws[WS_WE1 + g] = w1[g * 258 + 1] * s1v;
    float s2v = g2[g] / sqrtf(v2[g] + EPS);
    s2s[g] = s2v;
    t2s[g] = b2[g] - m2[g] * s2v;
    __syncthreads();
    float a0 = 0.f, a1 = 0.f;
    for (int f = 0; f < F; ++f) {
      float wv = w2[f * F + g];               // coalesced (g fastest)
      a0 = fmaf(pw[f]     * s2s[f], wv, a0);
      a1 = fmaf(pw[F + f] * s2s[f], wv, a1);
    }
    ws[WS_PF0 + g] = a0;
    ws[WS_PF1 + g] = a1;
    if (g < 2) {
      float c = pb[g];
      for (int f = 0; f < F; ++f) c += pw[g * F + f] * t2s[f];
      ws[WS_C + g] = c;
    }
    return;
  }
  __shared__ float4 ns4[64 * 32];              // 32 KB, xor-swizzled
  __shared__ float  wlds[2][8][F];             // 8 KB: [l/r][k][f]
  int t = threadIdx.x;
  int rc = blockIdx.x >> 4;                    // 16 row chunks of 64
  int gc = blockIdx.x & 15;                    // 16 g chunks of 8
  int r0 = rc * 64;
  int gb = gc * 8;
  const float4* node4 = reinterpret_cast<const float4*>(node) + (size_t)r0 * 32;
  #pragma unroll
  for (int k = 0; k < 16; ++k) {
    int L = k * 128 + t;                       // coalesced global float4 id
    int row = L >> 5, s = L & 31;
    ns4[row * 32 + (s ^ (row & 7))] = node4[L];
  }
  #pragma unroll
  for (int k = 0; k < 8; ++k) {                // coalesced weight-row copies
    const float* wrow = w1 + (size_t)(gb + k) * 258;
    wlds[0][k][t] = wrow[2 + t];
    wlds[1][k][t] = wrow[130 + t];
  }
  __syncthreads();
  int lane = t & 63;
  int wv = __builtin_amdgcn_readfirstlane(t >> 6);  // 0..1, SGPR
  int lx = lane & 7;
  int lbase = lane * 32;
  float accl[4] = {0.f, 0.f, 0.f, 0.f};
  float accr[4] = {0.f, 0.f, 0.f, 0.f};
  #pragma unroll 4
  for (int q = 0; q < 32; ++q) {
    float4 nv = ns4[lbase + (q ^ lx)];         // = node[row][4q..4q+3]
    #pragma unroll
    for (int k = 0; k < 4; ++k) {
      int kk = wv * 4 + k;
      float4 wl = *reinterpret_cast<const float4*>(&wlds[0][kk][q * 4]);  // uniform -> broadcast
      float4 wr = *reinterpret_cast<const float4*>(&wlds[1][kk][q * 4]);
      accl[k] = fmaf(nv.x, wl.x, accl[k]);
      accl[k] = fmaf(nv.y, wl.y, accl[k]);
      accl[k] = fmaf(nv.z, wl.z, accl[k]);
      accl[k] = fmaf(nv.w, wl.w, accl[k]);
      accr[k] = fmaf(nv.x, wr.x, accr[k]);
      accr[k] = fmaf(nv.y, wr.y, accr[k]);
      accr[k] = fmaf(nv.z, wr.z, accr[k]);
      accr[k] = fmaf(nv.w, wr.w, accr[k]);
    }
  }
  int row = r0 + lane;
  int g0 = gb + wv * 4;
  float4 ol, orr;
  #pragma unroll
  for (int k = 0; k < 4; ++k) {
    int g = g0 + k;
    float s1v = g1[g] / sqrtf(v1[g] + EPS);    // wave-uniform, tiny
    float t1v = b1[g] - m1[g] * s1v;
    (&ol.x)[k]  = fmaf(accl[k], s1v, t1v);
    (&orr.x)[k] = accr[k] * s1v;
  }
  *reinterpret_cast<float4*>(ws + WS_HL + (size_t)row * F + g0) = ol;
  *reinterpret_cast<float4*>(ws + WS_HR + (size_t)row * F + g0) = orr;
}

// ---------------------------------------------------------------- main
// grid (8,8,B), block 512: 32x32 (i,j) tile, 1x2 outputs per thread.
// 8 waves/block, 1 block/CU -> 2 waves/SIMD (TLP for ds_read latency).
// hl/hr tiles staged in LDS; WE/PF/C read as wave-uniform globals (s_load).
__global__ __launch_bounds__(512) void fused_main(
    const float* __restrict__ edge,
    const float* __restrict__ ws, float* __restrict__ out) {
  __shared__ float hls[32][132];
  __shared__ float hrs[32][132];
  int b = blockIdx.z, i0 = blockIdx.y * 32, j0 = blockIdx.x * 32;
  int t = threadIdx.x;                          // 0..511
  int ti = t >> 4, tj = t & 15;                 // ti 0..31, tj 0..15
  int i1 = i0 + ti, j1 = j0 + tj, j2 = j1 + 16;
  // issue edge loads early (independent of LDS staging)
  float2 e0 = *reinterpret_cast<const float2*>(edge + ((size_t)(b * N + i1) * N + j1) * 2);
  float2 e1 = *reinterpret_cast<const float2*>(edge + ((size_t)(b * N + i1) * N + j2) * 2);
  {
    int r = t >> 4, c0 = (t & 15) * 8;
    const float* sl = ws + WS_HL + (size_t)(b * N + i0 + r) * F + c0;
    const float* sr = ws + WS_HR + (size_t)(b * N + j0 + r) * F + c0;
    *reinterpret_cast<float4*>(&hls[r][c0])     = *reinterpret_cast<const float4*>(sl);
    *reinterpret_cast<float4*>(&hls[r][c0 + 4]) = *reinterpret_cast<const float4*>(sl + 4);
    *reinterpret_cast<float4*>(&hrs[r][c0])     = *reinterpret_cast<const float4*>(sr);
    *reinterpret_cast<float4*>(&hrs[r][c0 + 4]) = *reinterpret_cast<const float4*>(sr + 4);
  }
  __syncthreads();
  const float4* W0p = reinterpret_cast<const float4*>(ws + WS_WE0);  // uniform -> s_load
  const float4* W1p = reinterpret_cast<const float4*>(ws + WS_WE1);
  const float4* P0p = reinterpret_cast<const float4*>(ws + WS_PF0);
  const float4* P1p = reinterpret_cast<const float4*>(ws + WS_PF1);
  float a0x = 0.f, a0y = 0.f, a1x = 0.f, a1y = 0.f;
  #pragma unroll 4
  for (int gq = 0; gq < F / 4; ++gq) {
    int g = gq * 4;
    float4 L  = *reinterpret_cast<const float4*>(&hls[ti][g]);
    float4 R0 = *reinterpret_cast<const float4*>(&hrs[tj][g]);
    float4 R1 = *reinterpret_cast<const float4*>(&hrs[tj + 16][g]);
    float4 W0 = W0p[gq];
    float4 W1 = W1p[gq];
    float4 P0 = P0p[gq];
    float4 P1 = P1p[gq];
#define DO_COMP(K)                                                             \
    {                                                                          \
      float w0 = W0.K, w1v = W1.K, p0 = P0.K, p1 = P1.K;                       \
      float v;                                                                 \
      v = L.K + R0.K; v = fmaf(e0.x, w0, v); v = fmaf(e0.y, w1v, v);           \
      v = fmaxf(v, NSLOPE * v);                                                \
      a0x = fmaf(p0, v, a0x); a0y = fmaf(p1, v, a0y);                          \
      v = L.K + R1.K; v = fmaf(e1.x, w0, v); v = fmaf(e1.y, w1v, v);           \
      v = fmaxf(v, NSLOPE * v);                                                \
      a1x = fmaf(p0, v, a1x); a1y = fmaf(p1, v, a1y);                          \
    }
    DO_COMP(x) DO_COMP(y) DO_COMP(z) DO_COMP(w)
#undef DO_COMP
  }
  float c0 = ws[WS_C + 0], c1 = ws[WS_C + 1];
  float2 o;
  o.x = a0x + c0; o.y = a0y + c1;
  *reinterpret_cast<float2*>(out + ((size_t)(b * N + i1) * N + j1) * 2) = o;
  o.x = a1x + c0; o.y = a1y + c1;
  *reinterpret_cast<float2*>(out + ((size_t)(b * N + i1) * N + j2) * 2) = o;
}

extern "C" void kernel_launch(void* const* d_in, const int* in_sizes, int n_in,
                              void* d_out, int out_size, void* d_ws, size_t ws_size,
                              hipStream_t stream) {
  const float* node = (const float*)d_in[0];
  const float* edge = (const float*)d_in[1];
  const float* w1   = (const float*)d_in[2];
  const float* g1   = (const float*)d_in[3];
  const float* b1   = (const float*)d_in[4];
  const float* m1   = (const float*)d_in[5];
  const float* v1   = (const float*)d_in[6];
  const float* w2   = (const float*)d_in[7];
  const float* g2   = (const float*)d_in[8];
  const float* b2   = (const float*)d_in[9];
  const float* m2   = (const float*)d_in[10];
  const float* v2   = (const float*)d_in[11];
  const float* pw   = (const float*)d_in[12];
  const float* pb   = (const float*)d_in[13];
  float* ws  = (float*)d_ws;
  float* out = (float*)d_out;

  prep_all<<<257, 128, 0, stream>>>(node, w1, g1, b1, m1, v1, w2, g2, b2, m2,
                                    v2, pw, pb, ws);
  fused_main<<<dim3(N / 32, N / 32, B), 512, 0, stream>>>(edge, ws, out);
}